// Round 1
// baseline (244.939 us; speedup 1.0000x reference)
//
#include <hip/hip_runtime.h>
#include <math.h>

// Problem constants (from reference setup_inputs)
constexpr int N_TOK   = 131072;
constexpr int EMB     = 256;
constexpr long long N_ELEMS = (long long)N_TOK * EMB;   // 33554432
constexpr int NUM_LEVELS = 1024;
constexpr float BOUND = 512.0f;                          // num_levels / 2

constexpr int BLOCK = 256;
constexpr int GRID  = 2048;
constexpr int V4    = (int)(N_ELEMS / 4);                // 8388608 float4s
constexpr int PER_THREAD = V4 / (BLOCK * GRID);          // 16

// Kernel 1: q = round(512*tanh(z/T))*T, write out, accumulate sum((z-q)^2)
// per block into double partials[GRID].
__global__ __launch_bounds__(BLOCK) void fsq_main(
    const float4* __restrict__ z4,
    const float*  __restrict__ temp,
    float4*       __restrict__ out4,
    double*       __restrict__ partials)
{
    const float T    = temp[0];
    const float invT = 1.0f / T;

    float local = 0.0f;
    const int base = blockIdx.x * BLOCK + threadIdx.x;

    #pragma unroll
    for (int i = 0; i < PER_THREAD; ++i) {
        const int idx = base + i * (GRID * BLOCK);
        float4 zv = z4[idx];
        float4 qv;
        qv.x = rintf(BOUND * tanhf(zv.x * invT)) * T;
        qv.y = rintf(BOUND * tanhf(zv.y * invT)) * T;
        qv.z = rintf(BOUND * tanhf(zv.z * invT)) * T;
        qv.w = rintf(BOUND * tanhf(zv.w * invT)) * T;
        out4[idx] = qv;
        float dx = zv.x - qv.x;
        float dy = zv.y - qv.y;
        float dz = zv.z - qv.z;
        float dw = zv.w - qv.w;
        local += dx * dx + dy * dy + dz * dz + dw * dw;
    }

    // wave64 shuffle reduction
    #pragma unroll
    for (int off = 32; off > 0; off >>= 1)
        local += __shfl_down(local, off, 64);

    __shared__ double smem[BLOCK / 64];
    if ((threadIdx.x & 63) == 0) smem[threadIdx.x >> 6] = (double)local;
    __syncthreads();
    if (threadIdx.x == 0) {
        double s = 0.0;
        #pragma unroll
        for (int w = 0; w < BLOCK / 64; ++w) s += smem[w];
        partials[blockIdx.x] = s;
    }
}

// Kernel 2: one block. Reduce GRID double partials -> sum_sq; compute entropy
// term from usage_count; write total_loss to loss_out[0].
__global__ __launch_bounds__(256) void fsq_loss(
    const double* __restrict__ partials,
    const float*  __restrict__ usage,
    const float*  __restrict__ temp,
    float*        __restrict__ loss_out)
{
    const int tid = threadIdx.x;

    __shared__ double sd[256];
    __shared__ float  sf[256];

    // ---- sum of squared residuals ----
    double s = 0.0;
    for (int i = tid; i < GRID; i += 256) s += partials[i];
    sd[tid] = s;
    __syncthreads();
    for (int off = 128; off > 0; off >>= 1) {
        if (tid < off) sd[tid] += sd[tid + off];
        __syncthreads();
    }
    const double sum_sq = sd[0];
    __syncthreads();

    // ---- usage total ----
    float ut = 0.0f;
    for (int i = tid; i < NUM_LEVELS; i += 256) ut += usage[i];
    sf[tid] = ut;
    __syncthreads();
    for (int off = 128; off > 0; off >>= 1) {
        if (tid < off) sf[tid] += sf[tid + off];
        __syncthreads();
    }
    const float total = sf[0];
    __syncthreads();

    // ---- entropy: -(p * log2(p + 1e-10)).sum(), p = usage / max(total,1e-10) ----
    const float inv_total = 1.0f / fmaxf(total, 1e-10f);
    float e = 0.0f;
    for (int i = tid; i < NUM_LEVELS; i += 256) {
        float p = usage[i] * inv_total;
        e += p * log2f(p + 1e-10f);
    }
    sf[tid] = e;
    __syncthreads();
    for (int off = 128; off > 0; off >>= 1) {
        if (tid < off) sf[tid] += sf[tid + off];
        __syncthreads();
    }

    if (tid == 0) {
        float ent = -sf[0];                       // entropy rate
        float ent_rate = (total > 0.0f) ? ent : 0.0f;
        float entropy_loss = -ent_rate * 0.1f;
        float T = temp[0];
        // commitment_loss + codebook_loss = 2 * mean((z-q)^2) / T
        double mean = sum_sq / (double)N_ELEMS;
        loss_out[0] = (float)(2.0 * mean / (double)T) + entropy_loss;
    }
}

extern "C" void kernel_launch(void* const* d_in, const int* in_sizes, int n_in,
                              void* d_out, int out_size, void* d_ws, size_t ws_size,
                              hipStream_t stream) {
    const float* z     = (const float*)d_in[0];   // [131072, 256]
    // d_in[1] = codebook — unused: argmin/assignments is dead code in reference
    const float* temp  = (const float*)d_in[2];   // scalar
    const float* usage = (const float*)d_in[3];   // [1024]

    float*  out      = (float*)d_out;             // quantized [N_ELEMS] + loss [1]
    double* partials = (double*)d_ws;             // GRID doubles (16 KB)

    fsq_main<<<GRID, BLOCK, 0, stream>>>(
        (const float4*)z, temp, (float4*)out, partials);

    fsq_loss<<<1, 256, 0, stream>>>(
        partials, usage, temp, out + N_ELEMS);
}